// Round 15
// baseline (173.451 us; speedup 1.0000x reference)
//
#include <hip/hip_runtime.h>
#include <hip/hip_fp16.h>

// MPM P2G, two-pass LDS bucket sort + decode-once LDS gather (R18).
//
// node[g] = sum over particles in cells {g-1,g}^3 of trilinear w * (m, m*v)
// cell/node id: z + x*128 + y*128*128   (reference get_hash, dim==3)
//
// History: R2/R6/R8 -- per-particle scattered 16B stores cost a full 64B
// line each (MI355X L2 never merges partial lines across waves) -> placement
// must be wave-linear copies. R14 (PPB 4096->2048, 1->2 blocks/CU in
// region_bin) verified +9.5us. R15/R17 polish neutral at 152.9us.
// R16 (LDS-atomic scatter gather) regressed 2x (sorted records -> same-
// address LDS atomic serialization); reverted.
// R18: continue R14's occupancy ladder on region_bin -- 512-thread blocks,
// PPB 1024 (same 2 rec/thread). 16->8 waves/block lifts the wave-limit cap
// from 2 to 4 blocks/CU; 4 independent blocks interleave the 5 barrier
// phases (load/count/scan/scatter/copy) instead of 2.
//   A region_bin: block=1024 particles / 512 threads, LDS bucket by 512
//      regions (16^3 cells), atomicAdd run-reservation per region, LINEAR
//      LDS->global run copy (full-line wave-coalesced writes).
//   B tile_sort: block=region. ~1950 recs coalesced to registers, LDS
//      counting-sort by 2^3-cell tile (512/region, 8-wave scan), in-place
//      coalesced write-back + tile_off[513] table.
//   C gather: 125 contiguous tile segments, 2-wave-scan offset table,
//      segid lookup, decode-once LDS (b128), per-cell cap 3 + tiny LDS
//      overflow list, register accumulate, NT store.
//   D fixup: region-capacity overflow (13-sigma rare) exact fp32 atomics.
// Fallback: counting-sort-per-cell pipeline (verified), then naive scatter.

#define GRID_DIM   128
#define NUM_CELLS  (GRID_DIM * GRID_DIM * GRID_DIM)   // 2,097,152
#define INV_CELL   64.0f
#define OVF_MAX    65536
#define SCAN_BLKS  2048

#define NREG       512          // 8^3 regions of 16^3 cells
#define RCAP       2560         // records per region (mean 1953, ~13 sigma)
#define PPB        1024         // particles per Pass-A block (R18: was 2048)
#define ABLK       512          // Pass-A threads per block (R18: was 1024)
#define MAXCAP     3            // per-cell LDS slots in gather
#define NT2        512          // 2^3-cell tiles per region (8 per axis)
#define NSEG       125          // 5^3 covering 2-cell tiles per gather block
#define NREC       (729 * MAXCAP + 3)   // 2190, no pad
#define EPAD(sc)   ((sc) * 3)
#define SEGCAP     1024         // segid table (R ~ 477 +- 22, 24 sigma)

typedef float floatx4 __attribute__((ext_vector_type(4)));

__device__ __forceinline__ int cell_id(int ix, int iy, int iz) {
    return iz + ix * GRID_DIM + iy * (GRID_DIM * GRID_DIM);
}

__device__ __forceinline__ unsigned int q16(float f) {
    int q = (int)(f * 65536.0f + 0.5f);
    return (unsigned int)min(q, 65535);
}
__device__ __forceinline__ unsigned int f2h(float f) {
    return (unsigned int)__half_as_ushort(__float2half(f));
}
__device__ __forceinline__ float h2f(unsigned int b) {
    return __half2float(__ushort_as_half((unsigned short)(b & 0xffffu)));
}

// ---- Pass A: block-local bucket by region, coalesced run output -----------
__global__ __launch_bounds__(ABLK) void region_bin_kernel(
    const float* __restrict__ pos, const float* __restrict__ vel,
    const float* __restrict__ mass, unsigned int* __restrict__ region_cursor,
    uint4* __restrict__ regbuf, int* __restrict__ ovf_cnt,
    uint4* __restrict__ ovf_rec, unsigned int* __restrict__ ovf_reg, int n)
{
    __shared__ uint4 rec_lds[PPB];                 // 16 KB
    __shared__ unsigned short regof[PPB];          // 2 KB
    __shared__ unsigned int cnt[NREG];             // 2 KB
    __shared__ unsigned int lofs[NREG];            // 2 KB
    __shared__ unsigned int gbase[NREG];           // 2 KB
    __shared__ unsigned int wtot[8];

    int tid = threadIdx.x;
    int base_i = blockIdx.x * PPB;
    int blockn = min(PPB, n - base_i);

    if (tid < NREG) cnt[tid] = 0;
    __syncthreads();

    uint4 r_[2]; int reg_[2], rank_[2], val_[2];
    #pragma unroll
    for (int k = 0; k < 2; ++k) {
        int e = k * ABLK + tid;
        int i = base_i + e;
        val_[k] = (e < blockn);
        reg_[k] = 0; rank_[k] = 0;
        if (val_[k]) {
            float px = __builtin_nontemporal_load(&pos[3 * i + 0]);
            float py = __builtin_nontemporal_load(&pos[3 * i + 1]);
            float pz = __builtin_nontemporal_load(&pos[3 * i + 2]);
            float rx = px * INV_CELL, ry = py * INV_CELL, rz = pz * INV_CELL;
            float bx = floorf(rx), by = floorf(ry), bz = floorf(rz);
            float fx = rx - bx, fy = ry - by, fz = rz - bz;
            int ix = min(max((int)bx, 0), GRID_DIM - 1);
            int iy = min(max((int)by, 0), GRID_DIM - 1);
            int iz = min(max((int)bz, 0), GRID_DIM - 1);
            int reg = (iz >> 4) | ((ix >> 4) << 3) | ((iy >> 4) << 6);
            unsigned int cid = (unsigned int)((iz & 15) | ((ix & 15) << 4)
                                                        | ((iy & 15) << 8));
            float m  = __builtin_nontemporal_load(&mass[i]);
            float vx = __builtin_nontemporal_load(&vel[3 * i + 0]);
            float vy = __builtin_nontemporal_load(&vel[3 * i + 1]);
            float vz = __builtin_nontemporal_load(&vel[3 * i + 2]);
            uint4 r;
            r.x = q16(fx) | (q16(fy) << 16);
            r.y = q16(fz) | (f2h(m) << 16);
            r.z = f2h(vx) | (f2h(vy) << 16);
            r.w = f2h(vz) | (cid << 16);
            r_[k] = r;
            reg_[k] = reg;
            rank_[k] = (int)atomicAdd(&cnt[reg], 1u);
        }
    }
    __syncthreads();

    // exclusive scan of cnt[512] (8 waves, all 512 threads) -> lofs
    unsigned int c = cnt[tid];
    unsigned int v = c;
    #pragma unroll
    for (int d = 1; d < 64; d <<= 1) {
        unsigned int t = __shfl_up(v, d, 64);
        if ((tid & 63) >= d) v += t;
    }
    if ((tid & 63) == 63) wtot[tid >> 6] = v;
    __syncthreads();
    if (tid == 0) {
        unsigned int run = 0;
        #pragma unroll
        for (int w = 0; w < 8; ++w) { unsigned int t = wtot[w]; wtot[w] = run; run += t; }
    }
    __syncthreads();
    lofs[tid] = wtot[tid >> 6] + v - c;
    if (c) gbase[tid] = atomicAdd(&region_cursor[tid], c);
    __syncthreads();

    // LDS scatter: ordered by region
    #pragma unroll
    for (int k = 0; k < 2; ++k) {
        if (val_[k]) {
            int d = (int)lofs[reg_[k]] + rank_[k];
            rec_lds[d] = r_[k];
            regof[d] = (unsigned short)reg_[k];
        }
    }
    __syncthreads();

    // linear copy: consecutive lanes -> consecutive global addresses per run
    for (int e = tid; e < blockn; e += ABLK) {
        uint4 rr = rec_lds[e];
        int rg = (int)regof[e];
        unsigned int slot = gbase[rg] + (unsigned int)(e - (int)lofs[rg]);
        if (slot < (unsigned int)RCAP) {
            regbuf[(size_t)rg * RCAP + slot] = rr;
        } else {
            int o = atomicAdd(ovf_cnt, 1);
            if (o < OVF_MAX) { ovf_rec[o] = rr; ovf_reg[o] = (unsigned int)rg; }
        }
    }
}

// ---- Pass B: in-place counting sort by 2^3-cell tile within region --------
__global__ __launch_bounds__(1024) void tile_sort_kernel(
    uint4* __restrict__ regbuf, const unsigned int* __restrict__ region_cursor,
    unsigned int* __restrict__ tile_off)
{
    __shared__ uint4 out_lds[RCAP];                // 40 KB
    __shared__ unsigned int cnt[NT2];              // 2 KB (counts -> excl offs)
    __shared__ unsigned int wsum[8];

    int r = blockIdx.x;
    int tid = threadIdx.x;
    int cntR = (int)min(region_cursor[r], (unsigned int)RCAP);

    if (tid < NT2) cnt[tid] = 0;
    __syncthreads();

    uint4 rr_[3]; int t_[3], rk_[3], vl_[3];
    #pragma unroll
    for (int k = 0; k < 3; ++k) {
        int e = k * 1024 + tid;
        vl_[k] = (e < cntR);
        t_[k] = 0; rk_[k] = 0;
        if (vl_[k]) {
            uint4 rr = regbuf[(size_t)r * RCAP + e];
            unsigned int cid = rr.w >> 16;
            // 2^3-cell tile id: (z>>1) | (x>>1)<<3 | (y>>1)<<6
            int t = (int)(((cid & 15u) >> 1) | ((((cid >> 4) & 15u) >> 1) << 3)
                                             | ((((cid >> 8) & 15u) >> 1) << 6));
            rr_[k] = rr;
            t_[k] = t;
            rk_[k] = (int)atomicAdd(&cnt[t], 1u);
        }
    }
    __syncthreads();

    // exclusive scan of cnt[512] (8 waves), reuse cnt as offsets
    unsigned int c = 0, v = 0;
    if (tid < NT2) {
        c = cnt[tid];
        v = c;
        #pragma unroll
        for (int d = 1; d < 64; d <<= 1) {
            unsigned int t = __shfl_up(v, d, 64);
            if ((tid & 63) >= d) v += t;
        }
        if ((tid & 63) == 63) wsum[tid >> 6] = v;
    }
    __syncthreads();
    if (tid == 0) {
        unsigned int run = 0;
        #pragma unroll
        for (int w = 0; w < 8; ++w) { unsigned int t = wsum[w]; wsum[w] = run; run += t; }
    }
    __syncthreads();
    if (tid < NT2) cnt[tid] = wsum[tid >> 6] + v - c;   // exclusive offsets
    __syncthreads();

    #pragma unroll
    for (int k = 0; k < 3; ++k)
        if (vl_[k]) out_lds[(int)cnt[t_[k]] + rk_[k]] = rr_[k];
    __syncthreads();

    for (int e = tid; e < cntR; e += 1024)      // coalesced in-place write
        regbuf[(size_t)r * RCAP + e] = out_lds[e];
    if (tid < NT2) tile_off[(size_t)r * (NT2 + 1) + tid] = cnt[tid];
    if (tid == 0) tile_off[(size_t)r * (NT2 + 1) + NT2] = (unsigned int)cntR;
}

// ---- Pass C: segment-streamed node gather, decode-once LDS ----------------
__global__ __launch_bounds__(512) void tile_gather2_kernel(
    const uint4* __restrict__ regbuf, const unsigned int* __restrict__ tile_off,
    float4* __restrict__ out)
{
    __shared__ float4 recA[NREC];             // {fx,fy,fz, vx|vy bits} 35 KB
    __shared__ unsigned int recB[NREC];       // m | vz<<16            8.8 KB
    __shared__ unsigned int cnt_s[729];
    __shared__ unsigned int seg_gb[NSEG];
    __shared__ unsigned short seg_reg[NSEG];
    __shared__ unsigned int seg_off[NSEG + 1];
    __shared__ unsigned int wt2[2];
    __shared__ unsigned char segid[SEGCAP];   // 1 KB
    __shared__ int ovf_n;
    __shared__ short ovf_sc[64];
    __shared__ uint4 ovf_rec[64];

    int tid = threadIdx.x;
    // XCD-chunked swizzle (4096 % 8 == 0 -> simple bijective form)
    int swz = (blockIdx.x & 7) * 512 + (blockIdx.x >> 3);
    int bz = swz & 15;
    int bx = (swz >> 4) & 15;
    int by = swz >> 8;
    int g0x = bx * 8, g0y = by * 8, g0z = bz * 8;
    // first covering 2-cell tile per axis: floor((g0-1)/2) = 4*b - 1
    int Tz0 = bz * 4 - 1, Tx0 = bx * 4 - 1, Ty0 = by * 4 - 1;

    for (int s2 = tid; s2 < 729; s2 += 512) cnt_s[s2] = 0;
    if (tid == 0) ovf_n = 0;

    // segment table (125 segments) + 2-wave scan
    unsigned int c = 0, v = 0;
    if (tid < 128) {
        if (tid < NSEG) {
            int ltz = tid % 5, q = tid / 5, ltx = q % 5, lty = q / 5;
            int Tz = Tz0 + ltz, Tx = Tx0 + ltx, Ty = Ty0 + lty;
            unsigned int gb = 0; int reg = 0;
            if ((Tz >= 0) & (Tx >= 0) & (Ty >= 0)) {
                reg = (Tz >> 3) | ((Tx >> 3) << 3) | ((Ty >> 3) << 6);
                int tl = (Tz & 7) | ((Tx & 7) << 3) | ((Ty & 7) << 6);
                unsigned int o0 = tile_off[(size_t)reg * (NT2 + 1) + tl];
                unsigned int o1 = tile_off[(size_t)reg * (NT2 + 1) + tl + 1];
                c = o1 - o0;
                gb = (unsigned int)reg * RCAP + o0;
            }
            seg_reg[tid] = (unsigned short)reg;
            seg_gb[tid] = gb;
        }
        v = c;
        #pragma unroll
        for (int d = 1; d < 64; d <<= 1) {
            unsigned int t = __shfl_up(v, d, 64);
            if ((tid & 63) >= d) v += t;
        }
        if ((tid & 63) == 63) wt2[tid >> 6] = v;
    }
    __syncthreads();
    if (tid < 128) {
        unsigned int base = (tid >= 64) ? wt2[0] : 0u;
        if (tid < NSEG) seg_off[tid] = base + v - c;
        if (tid == NSEG - 1) seg_off[NSEG] = base + v;
    }
    __syncthreads();
    int R = (int)seg_off[NSEG];

    // fill segid lookup table (replaces per-record binary search)
    if (tid < NSEG) {
        unsigned int b = seg_off[tid];
        unsigned int e2 = min(seg_off[tid + 1], (unsigned int)SEGCAP);
        for (unsigned int q = b; q < e2; ++q) segid[q] = (unsigned char)tid;
    }
    __syncthreads();

    // ---- stage: grid-stride concatenated records, decode once -------------
    for (int r = tid; r < R; r += 512) {
        int s;
        if (r < SEGCAP) {
            s = (int)segid[r];
        } else {
            s = 0;                       // rare fallback: binary search
            #pragma unroll
            for (int step = 64; step >= 1; step >>= 1)
                if (s + step <= NSEG && (int)seg_off[s + step] <= r) s += step;
        }
        int j = r - (int)seg_off[s];
        uint4 rec = regbuf[seg_gb[s] + j];
        unsigned int cid = rec.w >> 16;
        int reg = (int)seg_reg[s];
        int cz = (reg & 7) * 16 + (int)(cid & 15u);
        int cx = ((reg >> 3) & 7) * 16 + (int)((cid >> 4) & 15u);
        int cy = ((reg >> 6) & 7) * 16 + (int)((cid >> 8) & 15u);
        int uz = cz - (g0z - 1), ux = cx - (g0x - 1), uy = cy - (g0y - 1);
        if (((unsigned)uz < 9u) & ((unsigned)ux < 9u) & ((unsigned)uy < 9u)) {
            int sc = uy * 81 + ux * 9 + uz;
            unsigned int j2 = atomicAdd(&cnt_s[sc], 1u);
            if (j2 < MAXCAP) {
                int e = EPAD(sc) + (int)j2;
                float fx = (float)(rec.x & 0xffffu) * (1.0f / 65536.0f);
                float fy = (float)(rec.x >> 16)     * (1.0f / 65536.0f);
                float fz = (float)(rec.y & 0xffffu) * (1.0f / 65536.0f);
                recA[e] = make_float4(fx, fy, fz, __uint_as_float(rec.z));
                recB[e] = (rec.y >> 16) | (rec.w << 16);
            } else {
                int o = atomicAdd(&ovf_n, 1);
                if (o < 64) { ovf_sc[o] = (short)sc; ovf_rec[o] = rec; }
                // o>=64 needs ~64 cells in one block at cnt>3: P < 1e-80.
            }
        }
    }
    __syncthreads();

    // ---- accumulate: thread owns node (tx,ty,tz) = tid --------------------
    int tz = tid & 7, tx = (tid >> 3) & 7, ty = tid >> 6;
    float a0 = 0.0f, a1 = 0.0f, a2 = 0.0f, a3 = 0.0f;

    #pragma unroll
    for (int dy = 0; dy < 2; ++dy) {
        #pragma unroll
        for (int dx = 0; dx < 2; ++dx) {
            int scb = (ty + dy) * 81 + (tx + dx) * 9 + tz;
            #pragma unroll
            for (int dz = 0; dz < 2; ++dz) {
                int sc = scb + dz;
                int cnt = min((int)cnt_s[sc], MAXCAP);
                int eb = EPAD(sc);
                for (int j = 0; j < cnt; ++j) {
                    float4 A = recA[eb + j];
                    unsigned int B = recB[eb + j];
                    unsigned int w3 = __float_as_uint(A.w);
                    // dx==1 -> staged cell == node's own cell -> (1-frac)
                    float wx = dx ? (1.0f - A.x) : A.x;
                    float wy = dy ? (1.0f - A.y) : A.y;
                    float wz = dz ? (1.0f - A.z) : A.z;
                    float sm = wx * wy * wz * h2f(B);
                    a0 += sm;
                    a1 += sm * h2f(w3);
                    a2 += sm * h2f(w3 >> 16);
                    a3 += sm * h2f(B >> 16);
                }
            }
        }
    }

    // ---- rare per-cell overflow: every thread scans the tiny list ---------
    int no = min(ovf_n, 64);
    for (int e2 = 0; e2 < no; ++e2) {
        int sc = (int)ovf_sc[e2];
        int uzv = sc % 9, t2 = sc / 9, uxv = t2 % 9, uyv = t2 / 9;
        int ddz = uzv - tz, ddx = uxv - tx, ddy = uyv - ty;
        if (((unsigned)ddz < 2u) & ((unsigned)ddx < 2u) & ((unsigned)ddy < 2u)) {
            uint4 rec = ovf_rec[e2];
            float fx = (float)(rec.x & 0xffffu) * (1.0f / 65536.0f);
            float fy = (float)(rec.x >> 16)     * (1.0f / 65536.0f);
            float fz = (float)(rec.y & 0xffffu) * (1.0f / 65536.0f);
            float wx = ddx ? (1.0f - fx) : fx;
            float wy = ddy ? (1.0f - fy) : fy;
            float wz = ddz ? (1.0f - fz) : fz;
            float sm = wx * wy * wz * h2f(rec.y >> 16);
            a0 += sm;
            a1 += sm * h2f(rec.z);
            a2 += sm * h2f(rec.z >> 16);
            a3 += sm * h2f(rec.w);
        }
    }

    int id = (g0z + tz) + (g0x + tx) * GRID_DIM
           + (g0y + ty) * (GRID_DIM * GRID_DIM);
    floatx4 vv = { a0, a1, a2, a3 };
    __builtin_nontemporal_store(vv, (floatx4*)&out[id]);
}

// ---- Pass D: region-capacity overflow fixup (packed records, rare) --------
__global__ __launch_bounds__(256) void fixup_packed_kernel(
    const int* __restrict__ ovf_cnt, const uint4* __restrict__ ovf_rec,
    const unsigned int* __restrict__ ovf_reg, float* __restrict__ out)
{
    int total = min(*ovf_cnt, OVF_MAX);
    for (int k = blockIdx.x * 256 + threadIdx.x; k < total; k += gridDim.x * 256) {
        uint4 rec = ovf_rec[k];
        unsigned int reg = ovf_reg[k];
        unsigned int cid = (rec.w >> 16) & 4095u;
        int iz = (int)(reg & 7u) * 16 + (int)(cid & 15u);
        int ix = (int)((reg >> 3) & 7u) * 16 + (int)((cid >> 4) & 15u);
        int iy = (int)((reg >> 6) & 7u) * 16 + (int)((cid >> 8) & 15u);
        float fx = (float)(rec.x & 0xffffu) * (1.0f / 65536.0f);
        float fy = (float)(rec.x >> 16)     * (1.0f / 65536.0f);
        float fz = (float)(rec.y & 0xffffu) * (1.0f / 65536.0f);
        float m  = h2f(rec.y >> 16);
        float vx = h2f(rec.z), vy = h2f(rec.z >> 16), vz = h2f(rec.w);
        float wx[2] = { 1.0f - fx, fx }, wy[2] = { 1.0f - fy, fy }, wz[2] = { 1.0f - fz, fz };
        #pragma unroll
        for (int a = 0; a < 2; ++a)
            #pragma unroll
            for (int b = 0; b < 2; ++b)
                #pragma unroll
                for (int c = 0; c < 2; ++c) {
                    int h = cell_id(ix + a, iy + b, iz + c);
                    bool valid = (h >= 0) && (h < NUM_CELLS);
                    int hc = min(max(h, 0), NUM_CELLS - 1);
                    float s = valid ? (wx[a] * wy[b] * wz[c]) : 0.0f;
                    float sm = s * m;
                    float* cell = out + 4 * (size_t)hc;
                    atomicAdd(cell + 0, sm);
                    atomicAdd(cell + 1, sm * vx);
                    atomicAdd(cell + 2, sm * vy);
                    atomicAdd(cell + 3, sm * vz);
                }
    }
}

// ======== fallback: counting-sort-per-cell pipeline (verified) =============
__global__ __launch_bounds__(256) void s_hist_kernel(
    const float* __restrict__ pos, int* __restrict__ counts, int n)
{
    int i = blockIdx.x * 256 + threadIdx.x;
    if (i >= n) return;
    int ix = min(max((int)floorf(pos[3 * i + 0] * INV_CELL), 0), GRID_DIM - 1);
    int iy = min(max((int)floorf(pos[3 * i + 1] * INV_CELL), 0), GRID_DIM - 1);
    int iz = min(max((int)floorf(pos[3 * i + 2] * INV_CELL), 0), GRID_DIM - 1);
    atomicAdd(&counts[cell_id(ix, iy, iz)], 1);
}

__global__ __launch_bounds__(256) void s_scan_partials_kernel(
    const int* __restrict__ counts, int* __restrict__ partials)
{
    __shared__ int red[256];
    int t = threadIdx.x;
    int4 v = ((const int4*)counts)[blockIdx.x * 256 + t];
    red[t] = v.x + v.y + v.z + v.w;
    __syncthreads();
    for (int off = 128; off > 0; off >>= 1) {
        if (t < off) red[t] += red[t + off];
        __syncthreads();
    }
    if (t == 0) partials[blockIdx.x] = red[0];
}

__global__ __launch_bounds__(1024) void s_scan_tops_kernel(int* __restrict__ partials)
{
    __shared__ int s[1024];
    int t = threadIdx.x;
    int p0 = partials[2 * t], p1 = partials[2 * t + 1];
    int sum = p0 + p1;
    s[t] = sum;
    __syncthreads();
    for (int off = 1; off < 1024; off <<= 1) {
        int x = (t >= off) ? s[t - off] : 0;
        __syncthreads();
        s[t] += x;
        __syncthreads();
    }
    int excl = s[t] - sum;
    partials[2 * t] = excl;
    partials[2 * t + 1] = excl + p0;
}

__global__ __launch_bounds__(256) void s_scan_final_kernel(
    const int* __restrict__ counts, const int* __restrict__ partials,
    int* __restrict__ offsets, int* __restrict__ cursors)
{
    __shared__ int s[256];
    int t = threadIdx.x;
    int g = blockIdx.x * 256 + t;
    int4 v = ((const int4*)counts)[g];
    int sum = v.x + v.y + v.z + v.w;
    s[t] = sum;
    __syncthreads();
    for (int off = 1; off < 256; off <<= 1) {
        int x = (t >= off) ? s[t - off] : 0;
        __syncthreads();
        s[t] += x;
        __syncthreads();
    }
    int run = partials[blockIdx.x] + s[t] - sum;
    int4 o = make_int4(run, run + v.x, run + v.x + v.y, run + v.x + v.y + v.z);
    ((int4*)offsets)[g] = o;
    ((int4*)cursors)[g] = o;
}

__global__ __launch_bounds__(256) void s_binplace_kernel(
    const float* __restrict__ pos, const float* __restrict__ vel,
    const float* __restrict__ mass, int* __restrict__ cursors,
    float4* __restrict__ records, int n)
{
    int i = blockIdx.x * 256 + threadIdx.x;
    if (i >= n) return;
    float rx = pos[3 * i + 0] * INV_CELL;
    float ry = pos[3 * i + 1] * INV_CELL;
    float rz = pos[3 * i + 2] * INV_CELL;
    int ix = min(max((int)floorf(rx), 0), GRID_DIM - 1);
    int iy = min(max((int)floorf(ry), 0), GRID_DIM - 1);
    int iz = min(max((int)floorf(rz), 0), GRID_DIM - 1);
    int slot = atomicAdd(&cursors[cell_id(ix, iy, iz)], 1);
    records[2 * slot + 0] = make_float4(rx, ry, rz, mass[i]);
    records[2 * slot + 1] = make_float4(vel[3 * i + 0], vel[3 * i + 1],
                                        vel[3 * i + 2], 0.0f);
}

__global__ __launch_bounds__(256) void s_node_gather_kernel(
    const float4* __restrict__ records, const int* __restrict__ offsets,
    const int* __restrict__ cursors, float4* __restrict__ out)
{
    int id = blockIdx.x * 256 + threadIdx.x;
    int gz = id & (GRID_DIM - 1);
    int gx = (id >> 7) & (GRID_DIM - 1);
    int gy = id >> 14;
    float fgx = (float)gx, fgy = (float)gy, fgz = (float)gz;
    float a0 = 0.0f, a1 = 0.0f, a2 = 0.0f, a3 = 0.0f;
    int z0 = max(gz - 1, 0), y0 = max(gy - 1, 0), x0 = max(gx - 1, 0);
    for (int cy = y0; cy <= gy; ++cy) {
        for (int cx = x0; cx <= gx; ++cx) {
            int cb = cx * GRID_DIM + cy * (GRID_DIM * GRID_DIM);
            int beg = offsets[cb + z0];
            int end = cursors[cb + gz];
            for (int p = beg; p < end; ++p) {
                float4 r0 = records[2 * p + 0];
                float4 r1 = records[2 * p + 1];
                float w = (1.0f - fabsf(r0.x - fgx)) *
                          (1.0f - fabsf(r0.y - fgy)) *
                          (1.0f - fabsf(r0.z - fgz));
                float sm = w * r0.w;
                a0 += sm; a1 += sm * r1.x; a2 += sm * r1.y; a3 += sm * r1.z;
            }
        }
    }
    out[id] = make_float4(a0, a1, a2, a3);
}

// ---- last-resort naive scatter --------------------------------------------
__global__ __launch_bounds__(256) void p2g_scatter_kernel(
    const float* __restrict__ pos, const float* __restrict__ vel,
    const float* __restrict__ mass, float* __restrict__ out, int n)
{
    int i = blockIdx.x * blockDim.x + threadIdx.x;
    if (i >= n) return;
    float px = pos[3 * i + 0] * INV_CELL;
    float py = pos[3 * i + 1] * INV_CELL;
    float pz = pos[3 * i + 2] * INV_CELL;
    float bx = floorf(px), by = floorf(py), bz = floorf(pz);
    float fx = px - bx, fy = py - by, fz = pz - bz;
    int ix = (int)bx, iy = (int)by, iz = (int)bz;
    float m = mass[i];
    float vx = vel[3 * i + 0], vy = vel[3 * i + 1], vz = vel[3 * i + 2];
    float wx[2] = { 1.0f - fx, fx }, wy[2] = { 1.0f - fy, fy }, wz[2] = { 1.0f - fz, fz };
    #pragma unroll
    for (int a = 0; a < 2; ++a)
        #pragma unroll
        for (int b = 0; b < 2; ++b)
            #pragma unroll
            for (int c = 0; c < 2; ++c) {
                int h = cell_id(ix + a, iy + b, iz + c);
                bool valid = (h >= 0) && (h < NUM_CELLS);
                int hc = min(max(h, 0), NUM_CELLS - 1);
                float s = valid ? (wx[a] * wy[b] * wz[c]) : 0.0f;
                float sm = s * m;
                float* cell = out + 4 * (size_t)hc;
                atomicAdd(cell + 0, sm);
                atomicAdd(cell + 1, sm * vx);
                atomicAdd(cell + 2, sm * vy);
                atomicAdd(cell + 3, sm * vz);
            }
}

extern "C" void kernel_launch(void* const* d_in, const int* in_sizes, int n_in,
                              void* d_out, int out_size, void* d_ws, size_t ws_size,
                              hipStream_t stream) {
    const float* pos  = (const float*)d_in[0];
    const float* vel  = (const float*)d_in[1];
    const float* mass = (const float*)d_in[2];
    float* out = (float*)d_out;
    int n = in_sizes[2];
    int blocks = (n + 255) / 256;

    // Two-pass ws: [cursor 2KB][ovf_cnt][tile_off 1.05MB][ovf_rec 1MB][ovf_reg 256KB][regbuf 20MB]
    size_t w_off_ovfcnt  = (size_t)NREG * 4;                        // 2048
    size_t w_off_tileoff = 4096;
    size_t w_off_ovfrec  = w_off_tileoff + (size_t)NREG * (NT2 + 1) * 4;
    size_t w_off_ovfreg  = w_off_ovfrec + (size_t)OVF_MAX * 16;
    size_t w_off_regbuf  = w_off_ovfreg + (size_t)OVF_MAX * 4;
    size_t need_twopass  = w_off_regbuf + (size_t)NREG * RCAP * 16;

    // Sorted-path ws: [counts/cursors 8MB][offsets 8MB][records n*32][partials]
    size_t s_off_offsets  = (size_t)NUM_CELLS * 4;
    size_t s_off_records  = s_off_offsets + (size_t)NUM_CELLS * 4;
    size_t s_off_partials = s_off_records + (size_t)n * 32;
    size_t need_sorted    = s_off_partials + (size_t)SCAN_BLKS * 4;

    if (ws_size >= need_twopass) {
        char* ws = (char*)d_ws;
        unsigned int* region_cursor = (unsigned int*)ws;
        int* ovf_cnt           = (int*)(ws + w_off_ovfcnt);
        unsigned int* tile_off = (unsigned int*)(ws + w_off_tileoff);
        uint4* ovf_rec         = (uint4*)(ws + w_off_ovfrec);
        unsigned int* ovf_reg  = (unsigned int*)(ws + w_off_ovfreg);
        uint4* regbuf          = (uint4*)(ws + w_off_regbuf);

        // single memset covers cursor (2048B) + ovf_cnt (4B)
        (void)hipMemsetAsync(ws, 0, 2112, stream);
        region_bin_kernel<<<(n + PPB - 1) / PPB, ABLK, 0, stream>>>(
            pos, vel, mass, region_cursor, regbuf, ovf_cnt, ovf_rec, ovf_reg, n);
        tile_sort_kernel<<<NREG, 1024, 0, stream>>>(regbuf, region_cursor,
                                                    tile_off);
        tile_gather2_kernel<<<4096, 512, 0, stream>>>(regbuf, tile_off,
                                                      (float4*)out);
        fixup_packed_kernel<<<16, 256, 0, stream>>>(ovf_cnt, ovf_rec,
                                                    ovf_reg, out);
    } else if (ws_size >= need_sorted) {
        char* ws = (char*)d_ws;
        int* counts   = (int*)ws;                    // reused as cursors
        int* offsets  = (int*)(ws + s_off_offsets);
        float4* records = (float4*)(ws + s_off_records);
        int* partials = (int*)(ws + s_off_partials);

        (void)hipMemsetAsync(counts, 0, (size_t)NUM_CELLS * 4, stream);
        s_hist_kernel<<<blocks, 256, 0, stream>>>(pos, counts, n);
        s_scan_partials_kernel<<<SCAN_BLKS, 256, 0, stream>>>(counts, partials);
        s_scan_tops_kernel<<<1, 1024, 0, stream>>>(partials);
        s_scan_final_kernel<<<SCAN_BLKS, 256, 0, stream>>>(counts, partials,
                                                           offsets, counts);
        s_binplace_kernel<<<blocks, 256, 0, stream>>>(pos, vel, mass, counts,
                                                      records, n);
        s_node_gather_kernel<<<NUM_CELLS / 256, 256, 0, stream>>>(
            records, offsets, counts, (float4*)out);
    } else {
        (void)hipMemsetAsync(out, 0, (size_t)out_size * sizeof(float), stream);
        p2g_scatter_kernel<<<blocks, 256, 0, stream>>>(pos, vel, mass, out, n);
    }
}

// Round 16
// 150.839 us; speedup vs baseline: 1.1499x; 1.1499x over previous
//
#include <hip/hip_runtime.h>
#include <hip/hip_fp16.h>

// MPM P2G, two-pass LDS bucket sort + decode-once LDS gather (R19 = R17 restore).
//
// node[g] = sum over particles in cells {g-1,g}^3 of trilinear w * (m, m*v)
// cell/node id: z + x*128 + y*128*128   (reference get_hash, dim==3)
//
// History: R2/R6/R8 -- per-particle scattered 16B stores cost a full 64B
// line each (MI355X L2 never merges partial lines across waves) -> placement
// must be wave-linear copies. R14 (PPB 2048, 2 blocks/CU region_bin)
// verified 154.0us; R15/R17 polish -> 152.9us (best). R16 (LDS-atomic
// scatter gather) regressed 2x (sorted records -> same-address LDS atomic
// serialization). R18 (PPB 1024) regressed +20us: mean run per
// (block,region) fell to 2 records = 32B < 64B line -> partial-line
// write-back returned + 2x scan overhead. CONSTRAINT LEARNED: runs must
// average >= 4 records (one full line) -> PPB >= 2048. R19 restores the
// verified-best R17 configuration.
//   A region_bin: block=2048 particles / 1024 threads, LDS bucket by 512
//      regions (16^3 cells), atomicAdd run-reservation per region, LINEAR
//      LDS->global run copy (full-line wave-coalesced writes).
//   B tile_sort: block=region. ~1950 recs coalesced to registers, LDS
//      counting-sort by 2^3-cell tile (512/region, 8-wave scan), in-place
//      coalesced write-back + tile_off[513] table.
//   C gather: 125 contiguous tile segments, 2-wave-scan offset table,
//      segid lookup, decode-once LDS (b128), per-cell cap 3 + tiny LDS
//      overflow list, register accumulate, NT store.
//   D fixup: region-capacity overflow (13-sigma rare) exact fp32 atomics.
// Fallback: counting-sort-per-cell pipeline (verified), then naive scatter.
//
// Plateau note: compulsory HBM traffic ~108MB ~= 17us; measured 153us is a
// structural floor of this 4-launch sorted-staging schedule (gather staging
// machinery ~43us + placement write-combining floor ~35us + sort ~11us +
// launches). Alternatives measured worse: direct-segment gather (R13,
// +7us), LDS-scatter gather (R16, +150us), smaller region_bin (R18, +20us).

#define GRID_DIM   128
#define NUM_CELLS  (GRID_DIM * GRID_DIM * GRID_DIM)   // 2,097,152
#define INV_CELL   64.0f
#define OVF_MAX    65536
#define SCAN_BLKS  2048

#define NREG       512          // 8^3 regions of 16^3 cells
#define RCAP       2560         // records per region (mean 1953, ~13 sigma)
#define PPB        2048         // particles per Pass-A block (>=2048: full-line runs)
#define MAXCAP     3            // per-cell LDS slots in gather
#define NT2        512          // 2^3-cell tiles per region (8 per axis)
#define NSEG       125          // 5^3 covering 2-cell tiles per gather block
#define NREC       (729 * MAXCAP + 3)   // 2190, no pad
#define EPAD(sc)   ((sc) * 3)
#define SEGCAP     1024         // segid table (R ~ 477 +- 22, 24 sigma)

typedef float floatx4 __attribute__((ext_vector_type(4)));

__device__ __forceinline__ int cell_id(int ix, int iy, int iz) {
    return iz + ix * GRID_DIM + iy * (GRID_DIM * GRID_DIM);
}

__device__ __forceinline__ unsigned int q16(float f) {
    int q = (int)(f * 65536.0f + 0.5f);
    return (unsigned int)min(q, 65535);
}
__device__ __forceinline__ unsigned int f2h(float f) {
    return (unsigned int)__half_as_ushort(__float2half(f));
}
__device__ __forceinline__ float h2f(unsigned int b) {
    return __half2float(__ushort_as_half((unsigned short)(b & 0xffffu)));
}

// ---- Pass A: block-local bucket by region, coalesced run output -----------
__global__ __launch_bounds__(1024) void region_bin_kernel(
    const float* __restrict__ pos, const float* __restrict__ vel,
    const float* __restrict__ mass, unsigned int* __restrict__ region_cursor,
    uint4* __restrict__ regbuf, int* __restrict__ ovf_cnt,
    uint4* __restrict__ ovf_rec, unsigned int* __restrict__ ovf_reg, int n)
{
    __shared__ uint4 rec_lds[PPB];                 // 32 KB
    __shared__ unsigned short regof[PPB];          // 4 KB
    __shared__ unsigned int cnt[NREG];             // 2 KB
    __shared__ unsigned int lofs[NREG];            // 2 KB
    __shared__ unsigned int gbase[NREG];           // 2 KB
    __shared__ unsigned int wtot[8];

    int tid = threadIdx.x;
    int base_i = blockIdx.x * PPB;
    int blockn = min(PPB, n - base_i);

    if (tid < NREG) cnt[tid] = 0;
    __syncthreads();

    uint4 r_[2]; int reg_[2], rank_[2], val_[2];
    #pragma unroll
    for (int k = 0; k < 2; ++k) {
        int e = k * 1024 + tid;
        int i = base_i + e;
        val_[k] = (e < blockn);
        reg_[k] = 0; rank_[k] = 0;
        if (val_[k]) {
            float px = __builtin_nontemporal_load(&pos[3 * i + 0]);
            float py = __builtin_nontemporal_load(&pos[3 * i + 1]);
            float pz = __builtin_nontemporal_load(&pos[3 * i + 2]);
            float rx = px * INV_CELL, ry = py * INV_CELL, rz = pz * INV_CELL;
            float bx = floorf(rx), by = floorf(ry), bz = floorf(rz);
            float fx = rx - bx, fy = ry - by, fz = rz - bz;
            int ix = min(max((int)bx, 0), GRID_DIM - 1);
            int iy = min(max((int)by, 0), GRID_DIM - 1);
            int iz = min(max((int)bz, 0), GRID_DIM - 1);
            int reg = (iz >> 4) | ((ix >> 4) << 3) | ((iy >> 4) << 6);
            unsigned int cid = (unsigned int)((iz & 15) | ((ix & 15) << 4)
                                                        | ((iy & 15) << 8));
            float m  = __builtin_nontemporal_load(&mass[i]);
            float vx = __builtin_nontemporal_load(&vel[3 * i + 0]);
            float vy = __builtin_nontemporal_load(&vel[3 * i + 1]);
            float vz = __builtin_nontemporal_load(&vel[3 * i + 2]);
            uint4 r;
            r.x = q16(fx) | (q16(fy) << 16);
            r.y = q16(fz) | (f2h(m) << 16);
            r.z = f2h(vx) | (f2h(vy) << 16);
            r.w = f2h(vz) | (cid << 16);
            r_[k] = r;
            reg_[k] = reg;
            rank_[k] = (int)atomicAdd(&cnt[reg], 1u);
        }
    }
    __syncthreads();

    // exclusive scan of cnt[512] (8 waves) -> lofs; reserve global runs
    unsigned int c = 0, v = 0;
    if (tid < NREG) {
        c = cnt[tid];
        v = c;
        #pragma unroll
        for (int d = 1; d < 64; d <<= 1) {
            unsigned int t = __shfl_up(v, d, 64);
            if ((tid & 63) >= d) v += t;
        }
        if ((tid & 63) == 63) wtot[tid >> 6] = v;
    }
    __syncthreads();
    if (tid == 0) {
        unsigned int run = 0;
        #pragma unroll
        for (int w = 0; w < 8; ++w) { unsigned int t = wtot[w]; wtot[w] = run; run += t; }
    }
    __syncthreads();
    if (tid < NREG) {
        lofs[tid] = wtot[tid >> 6] + v - c;
        if (c) gbase[tid] = atomicAdd(&region_cursor[tid], c);
    }
    __syncthreads();

    // LDS scatter: ordered by region
    #pragma unroll
    for (int k = 0; k < 2; ++k) {
        if (val_[k]) {
            int d = (int)lofs[reg_[k]] + rank_[k];
            rec_lds[d] = r_[k];
            regof[d] = (unsigned short)reg_[k];
        }
    }
    __syncthreads();

    // linear copy: consecutive lanes -> consecutive global addresses per run
    for (int e = tid; e < blockn; e += 1024) {
        uint4 rr = rec_lds[e];
        int rg = (int)regof[e];
        unsigned int slot = gbase[rg] + (unsigned int)(e - (int)lofs[rg]);
        if (slot < (unsigned int)RCAP) {
            regbuf[(size_t)rg * RCAP + slot] = rr;
        } else {
            int o = atomicAdd(ovf_cnt, 1);
            if (o < OVF_MAX) { ovf_rec[o] = rr; ovf_reg[o] = (unsigned int)rg; }
        }
    }
}

// ---- Pass B: in-place counting sort by 2^3-cell tile within region --------
__global__ __launch_bounds__(1024) void tile_sort_kernel(
    uint4* __restrict__ regbuf, const unsigned int* __restrict__ region_cursor,
    unsigned int* __restrict__ tile_off)
{
    __shared__ uint4 out_lds[RCAP];                // 40 KB
    __shared__ unsigned int cnt[NT2];              // 2 KB (counts -> excl offs)
    __shared__ unsigned int wsum[8];

    int r = blockIdx.x;
    int tid = threadIdx.x;
    int cntR = (int)min(region_cursor[r], (unsigned int)RCAP);

    if (tid < NT2) cnt[tid] = 0;
    __syncthreads();

    uint4 rr_[3]; int t_[3], rk_[3], vl_[3];
    #pragma unroll
    for (int k = 0; k < 3; ++k) {
        int e = k * 1024 + tid;
        vl_[k] = (e < cntR);
        t_[k] = 0; rk_[k] = 0;
        if (vl_[k]) {
            uint4 rr = regbuf[(size_t)r * RCAP + e];
            unsigned int cid = rr.w >> 16;
            // 2^3-cell tile id: (z>>1) | (x>>1)<<3 | (y>>1)<<6
            int t = (int)(((cid & 15u) >> 1) | ((((cid >> 4) & 15u) >> 1) << 3)
                                             | ((((cid >> 8) & 15u) >> 1) << 6));
            rr_[k] = rr;
            t_[k] = t;
            rk_[k] = (int)atomicAdd(&cnt[t], 1u);
        }
    }
    __syncthreads();

    // exclusive scan of cnt[512] (8 waves), reuse cnt as offsets
    unsigned int c = 0, v = 0;
    if (tid < NT2) {
        c = cnt[tid];
        v = c;
        #pragma unroll
        for (int d = 1; d < 64; d <<= 1) {
            unsigned int t = __shfl_up(v, d, 64);
            if ((tid & 63) >= d) v += t;
        }
        if ((tid & 63) == 63) wsum[tid >> 6] = v;
    }
    __syncthreads();
    if (tid == 0) {
        unsigned int run = 0;
        #pragma unroll
        for (int w = 0; w < 8; ++w) { unsigned int t = wsum[w]; wsum[w] = run; run += t; }
    }
    __syncthreads();
    if (tid < NT2) cnt[tid] = wsum[tid >> 6] + v - c;   // exclusive offsets
    __syncthreads();

    #pragma unroll
    for (int k = 0; k < 3; ++k)
        if (vl_[k]) out_lds[(int)cnt[t_[k]] + rk_[k]] = rr_[k];
    __syncthreads();

    for (int e = tid; e < cntR; e += 1024)      // coalesced in-place write
        regbuf[(size_t)r * RCAP + e] = out_lds[e];
    if (tid < NT2) tile_off[(size_t)r * (NT2 + 1) + tid] = cnt[tid];
    if (tid == 0) tile_off[(size_t)r * (NT2 + 1) + NT2] = (unsigned int)cntR;
}

// ---- Pass C: segment-streamed node gather, decode-once LDS ----------------
__global__ __launch_bounds__(512) void tile_gather2_kernel(
    const uint4* __restrict__ regbuf, const unsigned int* __restrict__ tile_off,
    float4* __restrict__ out)
{
    __shared__ float4 recA[NREC];             // {fx,fy,fz, vx|vy bits} 35 KB
    __shared__ unsigned int recB[NREC];       // m | vz<<16            8.8 KB
    __shared__ unsigned int cnt_s[729];
    __shared__ unsigned int seg_gb[NSEG];
    __shared__ unsigned short seg_reg[NSEG];
    __shared__ unsigned int seg_off[NSEG + 1];
    __shared__ unsigned int wt2[2];
    __shared__ unsigned char segid[SEGCAP];   // 1 KB
    __shared__ int ovf_n;
    __shared__ short ovf_sc[64];
    __shared__ uint4 ovf_rec[64];

    int tid = threadIdx.x;
    // XCD-chunked swizzle (4096 % 8 == 0 -> simple bijective form)
    int swz = (blockIdx.x & 7) * 512 + (blockIdx.x >> 3);
    int bz = swz & 15;
    int bx = (swz >> 4) & 15;
    int by = swz >> 8;
    int g0x = bx * 8, g0y = by * 8, g0z = bz * 8;
    // first covering 2-cell tile per axis: floor((g0-1)/2) = 4*b - 1
    int Tz0 = bz * 4 - 1, Tx0 = bx * 4 - 1, Ty0 = by * 4 - 1;

    for (int s2 = tid; s2 < 729; s2 += 512) cnt_s[s2] = 0;
    if (tid == 0) ovf_n = 0;

    // segment table (125 segments) + 2-wave scan
    unsigned int c = 0, v = 0;
    if (tid < 128) {
        if (tid < NSEG) {
            int ltz = tid % 5, q = tid / 5, ltx = q % 5, lty = q / 5;
            int Tz = Tz0 + ltz, Tx = Tx0 + ltx, Ty = Ty0 + lty;
            unsigned int gb = 0; int reg = 0;
            if ((Tz >= 0) & (Tx >= 0) & (Ty >= 0)) {
                reg = (Tz >> 3) | ((Tx >> 3) << 3) | ((Ty >> 3) << 6);
                int tl = (Tz & 7) | ((Tx & 7) << 3) | ((Ty & 7) << 6);
                unsigned int o0 = tile_off[(size_t)reg * (NT2 + 1) + tl];
                unsigned int o1 = tile_off[(size_t)reg * (NT2 + 1) + tl + 1];
                c = o1 - o0;
                gb = (unsigned int)reg * RCAP + o0;
            }
            seg_reg[tid] = (unsigned short)reg;
            seg_gb[tid] = gb;
        }
        v = c;
        #pragma unroll
        for (int d = 1; d < 64; d <<= 1) {
            unsigned int t = __shfl_up(v, d, 64);
            if ((tid & 63) >= d) v += t;
        }
        if ((tid & 63) == 63) wt2[tid >> 6] = v;
    }
    __syncthreads();
    if (tid < 128) {
        unsigned int base = (tid >= 64) ? wt2[0] : 0u;
        if (tid < NSEG) seg_off[tid] = base + v - c;
        if (tid == NSEG - 1) seg_off[NSEG] = base + v;
    }
    __syncthreads();
    int R = (int)seg_off[NSEG];

    // fill segid lookup table (replaces per-record binary search)
    if (tid < NSEG) {
        unsigned int b = seg_off[tid];
        unsigned int e2 = min(seg_off[tid + 1], (unsigned int)SEGCAP);
        for (unsigned int q = b; q < e2; ++q) segid[q] = (unsigned char)tid;
    }
    __syncthreads();

    // ---- stage: grid-stride concatenated records, decode once -------------
    for (int r = tid; r < R; r += 512) {
        int s;
        if (r < SEGCAP) {
            s = (int)segid[r];
        } else {
            s = 0;                       // rare fallback: binary search
            #pragma unroll
            for (int step = 64; step >= 1; step >>= 1)
                if (s + step <= NSEG && (int)seg_off[s + step] <= r) s += step;
        }
        int j = r - (int)seg_off[s];
        uint4 rec = regbuf[seg_gb[s] + j];
        unsigned int cid = rec.w >> 16;
        int reg = (int)seg_reg[s];
        int cz = (reg & 7) * 16 + (int)(cid & 15u);
        int cx = ((reg >> 3) & 7) * 16 + (int)((cid >> 4) & 15u);
        int cy = ((reg >> 6) & 7) * 16 + (int)((cid >> 8) & 15u);
        int uz = cz - (g0z - 1), ux = cx - (g0x - 1), uy = cy - (g0y - 1);
        if (((unsigned)uz < 9u) & ((unsigned)ux < 9u) & ((unsigned)uy < 9u)) {
            int sc = uy * 81 + ux * 9 + uz;
            unsigned int j2 = atomicAdd(&cnt_s[sc], 1u);
            if (j2 < MAXCAP) {
                int e = EPAD(sc) + (int)j2;
                float fx = (float)(rec.x & 0xffffu) * (1.0f / 65536.0f);
                float fy = (float)(rec.x >> 16)     * (1.0f / 65536.0f);
                float fz = (float)(rec.y & 0xffffu) * (1.0f / 65536.0f);
                recA[e] = make_float4(fx, fy, fz, __uint_as_float(rec.z));
                recB[e] = (rec.y >> 16) | (rec.w << 16);
            } else {
                int o = atomicAdd(&ovf_n, 1);
                if (o < 64) { ovf_sc[o] = (short)sc; ovf_rec[o] = rec; }
                // o>=64 needs ~64 cells in one block at cnt>3: P < 1e-80.
            }
        }
    }
    __syncthreads();

    // ---- accumulate: thread owns node (tx,ty,tz) = tid --------------------
    int tz = tid & 7, tx = (tid >> 3) & 7, ty = tid >> 6;
    float a0 = 0.0f, a1 = 0.0f, a2 = 0.0f, a3 = 0.0f;

    #pragma unroll
    for (int dy = 0; dy < 2; ++dy) {
        #pragma unroll
        for (int dx = 0; dx < 2; ++dx) {
            int scb = (ty + dy) * 81 + (tx + dx) * 9 + tz;
            #pragma unroll
            for (int dz = 0; dz < 2; ++dz) {
                int sc = scb + dz;
                int cnt = min((int)cnt_s[sc], MAXCAP);
                int eb = EPAD(sc);
                for (int j = 0; j < cnt; ++j) {
                    float4 A = recA[eb + j];
                    unsigned int B = recB[eb + j];
                    unsigned int w3 = __float_as_uint(A.w);
                    // dx==1 -> staged cell == node's own cell -> (1-frac)
                    float wx = dx ? (1.0f - A.x) : A.x;
                    float wy = dy ? (1.0f - A.y) : A.y;
                    float wz = dz ? (1.0f - A.z) : A.z;
                    float sm = wx * wy * wz * h2f(B);
                    a0 += sm;
                    a1 += sm * h2f(w3);
                    a2 += sm * h2f(w3 >> 16);
                    a3 += sm * h2f(B >> 16);
                }
            }
        }
    }

    // ---- rare per-cell overflow: every thread scans the tiny list ---------
    int no = min(ovf_n, 64);
    for (int e2 = 0; e2 < no; ++e2) {
        int sc = (int)ovf_sc[e2];
        int uzv = sc % 9, t2 = sc / 9, uxv = t2 % 9, uyv = t2 / 9;
        int ddz = uzv - tz, ddx = uxv - tx, ddy = uyv - ty;
        if (((unsigned)ddz < 2u) & ((unsigned)ddx < 2u) & ((unsigned)ddy < 2u)) {
            uint4 rec = ovf_rec[e2];
            float fx = (float)(rec.x & 0xffffu) * (1.0f / 65536.0f);
            float fy = (float)(rec.x >> 16)     * (1.0f / 65536.0f);
            float fz = (float)(rec.y & 0xffffu) * (1.0f / 65536.0f);
            float wx = ddx ? (1.0f - fx) : fx;
            float wy = ddy ? (1.0f - fy) : fy;
            float wz = ddz ? (1.0f - fz) : fz;
            float sm = wx * wy * wz * h2f(rec.y >> 16);
            a0 += sm;
            a1 += sm * h2f(rec.z);
            a2 += sm * h2f(rec.z >> 16);
            a3 += sm * h2f(rec.w);
        }
    }

    int id = (g0z + tz) + (g0x + tx) * GRID_DIM
           + (g0y + ty) * (GRID_DIM * GRID_DIM);
    floatx4 vv = { a0, a1, a2, a3 };
    __builtin_nontemporal_store(vv, (floatx4*)&out[id]);
}

// ---- Pass D: region-capacity overflow fixup (packed records, rare) --------
__global__ __launch_bounds__(256) void fixup_packed_kernel(
    const int* __restrict__ ovf_cnt, const uint4* __restrict__ ovf_rec,
    const unsigned int* __restrict__ ovf_reg, float* __restrict__ out)
{
    int total = min(*ovf_cnt, OVF_MAX);
    for (int k = blockIdx.x * 256 + threadIdx.x; k < total; k += gridDim.x * 256) {
        uint4 rec = ovf_rec[k];
        unsigned int reg = ovf_reg[k];
        unsigned int cid = (rec.w >> 16) & 4095u;
        int iz = (int)(reg & 7u) * 16 + (int)(cid & 15u);
        int ix = (int)((reg >> 3) & 7u) * 16 + (int)((cid >> 4) & 15u);
        int iy = (int)((reg >> 6) & 7u) * 16 + (int)((cid >> 8) & 15u);
        float fx = (float)(rec.x & 0xffffu) * (1.0f / 65536.0f);
        float fy = (float)(rec.x >> 16)     * (1.0f / 65536.0f);
        float fz = (float)(rec.y & 0xffffu) * (1.0f / 65536.0f);
        float m  = h2f(rec.y >> 16);
        float vx = h2f(rec.z), vy = h2f(rec.z >> 16), vz = h2f(rec.w);
        float wx[2] = { 1.0f - fx, fx }, wy[2] = { 1.0f - fy, fy }, wz[2] = { 1.0f - fz, fz };
        #pragma unroll
        for (int a = 0; a < 2; ++a)
            #pragma unroll
            for (int b = 0; b < 2; ++b)
                #pragma unroll
                for (int c = 0; c < 2; ++c) {
                    int h = cell_id(ix + a, iy + b, iz + c);
                    bool valid = (h >= 0) && (h < NUM_CELLS);
                    int hc = min(max(h, 0), NUM_CELLS - 1);
                    float s = valid ? (wx[a] * wy[b] * wz[c]) : 0.0f;
                    float sm = s * m;
                    float* cell = out + 4 * (size_t)hc;
                    atomicAdd(cell + 0, sm);
                    atomicAdd(cell + 1, sm * vx);
                    atomicAdd(cell + 2, sm * vy);
                    atomicAdd(cell + 3, sm * vz);
                }
    }
}

// ======== fallback: counting-sort-per-cell pipeline (verified) =============
__global__ __launch_bounds__(256) void s_hist_kernel(
    const float* __restrict__ pos, int* __restrict__ counts, int n)
{
    int i = blockIdx.x * 256 + threadIdx.x;
    if (i >= n) return;
    int ix = min(max((int)floorf(pos[3 * i + 0] * INV_CELL), 0), GRID_DIM - 1);
    int iy = min(max((int)floorf(pos[3 * i + 1] * INV_CELL), 0), GRID_DIM - 1);
    int iz = min(max((int)floorf(pos[3 * i + 2] * INV_CELL), 0), GRID_DIM - 1);
    atomicAdd(&counts[cell_id(ix, iy, iz)], 1);
}

__global__ __launch_bounds__(256) void s_scan_partials_kernel(
    const int* __restrict__ counts, int* __restrict__ partials)
{
    __shared__ int red[256];
    int t = threadIdx.x;
    int4 v = ((const int4*)counts)[blockIdx.x * 256 + t];
    red[t] = v.x + v.y + v.z + v.w;
    __syncthreads();
    for (int off = 128; off > 0; off >>= 1) {
        if (t < off) red[t] += red[t + off];
        __syncthreads();
    }
    if (t == 0) partials[blockIdx.x] = red[0];
}

__global__ __launch_bounds__(1024) void s_scan_tops_kernel(int* __restrict__ partials)
{
    __shared__ int s[1024];
    int t = threadIdx.x;
    int p0 = partials[2 * t], p1 = partials[2 * t + 1];
    int sum = p0 + p1;
    s[t] = sum;
    __syncthreads();
    for (int off = 1; off < 1024; off <<= 1) {
        int x = (t >= off) ? s[t - off] : 0;
        __syncthreads();
        s[t] += x;
        __syncthreads();
    }
    int excl = s[t] - sum;
    partials[2 * t] = excl;
    partials[2 * t + 1] = excl + p0;
}

__global__ __launch_bounds__(256) void s_scan_final_kernel(
    const int* __restrict__ counts, const int* __restrict__ partials,
    int* __restrict__ offsets, int* __restrict__ cursors)
{
    __shared__ int s[256];
    int t = threadIdx.x;
    int g = blockIdx.x * 256 + t;
    int4 v = ((const int4*)counts)[g];
    int sum = v.x + v.y + v.z + v.w;
    s[t] = sum;
    __syncthreads();
    for (int off = 1; off < 256; off <<= 1) {
        int x = (t >= off) ? s[t - off] : 0;
        __syncthreads();
        s[t] += x;
        __syncthreads();
    }
    int run = partials[blockIdx.x] + s[t] - sum;
    int4 o = make_int4(run, run + v.x, run + v.x + v.y, run + v.x + v.y + v.z);
    ((int4*)offsets)[g] = o;
    ((int4*)cursors)[g] = o;
}

__global__ __launch_bounds__(256) void s_binplace_kernel(
    const float* __restrict__ pos, const float* __restrict__ vel,
    const float* __restrict__ mass, int* __restrict__ cursors,
    float4* __restrict__ records, int n)
{
    int i = blockIdx.x * 256 + threadIdx.x;
    if (i >= n) return;
    float rx = pos[3 * i + 0] * INV_CELL;
    float ry = pos[3 * i + 1] * INV_CELL;
    float rz = pos[3 * i + 2] * INV_CELL;
    int ix = min(max((int)floorf(rx), 0), GRID_DIM - 1);
    int iy = min(max((int)floorf(ry), 0), GRID_DIM - 1);
    int iz = min(max((int)floorf(rz), 0), GRID_DIM - 1);
    int slot = atomicAdd(&cursors[cell_id(ix, iy, iz)], 1);
    records[2 * slot + 0] = make_float4(rx, ry, rz, mass[i]);
    records[2 * slot + 1] = make_float4(vel[3 * i + 0], vel[3 * i + 1],
                                        vel[3 * i + 2], 0.0f);
}

__global__ __launch_bounds__(256) void s_node_gather_kernel(
    const float4* __restrict__ records, const int* __restrict__ offsets,
    const int* __restrict__ cursors, float4* __restrict__ out)
{
    int id = blockIdx.x * 256 + threadIdx.x;
    int gz = id & (GRID_DIM - 1);
    int gx = (id >> 7) & (GRID_DIM - 1);
    int gy = id >> 14;
    float fgx = (float)gx, fgy = (float)gy, fgz = (float)gz;
    float a0 = 0.0f, a1 = 0.0f, a2 = 0.0f, a3 = 0.0f;
    int z0 = max(gz - 1, 0), y0 = max(gy - 1, 0), x0 = max(gx - 1, 0);
    for (int cy = y0; cy <= gy; ++cy) {
        for (int cx = x0; cx <= gx; ++cx) {
            int cb = cx * GRID_DIM + cy * (GRID_DIM * GRID_DIM);
            int beg = offsets[cb + z0];
            int end = cursors[cb + gz];
            for (int p = beg; p < end; ++p) {
                float4 r0 = records[2 * p + 0];
                float4 r1 = records[2 * p + 1];
                float w = (1.0f - fabsf(r0.x - fgx)) *
                          (1.0f - fabsf(r0.y - fgy)) *
                          (1.0f - fabsf(r0.z - fgz));
                float sm = w * r0.w;
                a0 += sm; a1 += sm * r1.x; a2 += sm * r1.y; a3 += sm * r1.z;
            }
        }
    }
    out[id] = make_float4(a0, a1, a2, a3);
}

// ---- last-resort naive scatter --------------------------------------------
__global__ __launch_bounds__(256) void p2g_scatter_kernel(
    const float* __restrict__ pos, const float* __restrict__ vel,
    const float* __restrict__ mass, float* __restrict__ out, int n)
{
    int i = blockIdx.x * blockDim.x + threadIdx.x;
    if (i >= n) return;
    float px = pos[3 * i + 0] * INV_CELL;
    float py = pos[3 * i + 1] * INV_CELL;
    float pz = pos[3 * i + 2] * INV_CELL;
    float bx = floorf(px), by = floorf(py), bz = floorf(pz);
    float fx = px - bx, fy = py - by, fz = pz - bz;
    int ix = (int)bx, iy = (int)by, iz = (int)bz;
    float m = mass[i];
    float vx = vel[3 * i + 0], vy = vel[3 * i + 1], vz = vel[3 * i + 2];
    float wx[2] = { 1.0f - fx, fx }, wy[2] = { 1.0f - fy, fy }, wz[2] = { 1.0f - fz, fz };
    #pragma unroll
    for (int a = 0; a < 2; ++a)
        #pragma unroll
        for (int b = 0; b < 2; ++b)
            #pragma unroll
            for (int c = 0; c < 2; ++c) {
                int h = cell_id(ix + a, iy + b, iz + c);
                bool valid = (h >= 0) && (h < NUM_CELLS);
                int hc = min(max(h, 0), NUM_CELLS - 1);
                float s = valid ? (wx[a] * wy[b] * wz[c]) : 0.0f;
                float sm = s * m;
                float* cell = out + 4 * (size_t)hc;
                atomicAdd(cell + 0, sm);
                atomicAdd(cell + 1, sm * vx);
                atomicAdd(cell + 2, sm * vy);
                atomicAdd(cell + 3, sm * vz);
            }
}

extern "C" void kernel_launch(void* const* d_in, const int* in_sizes, int n_in,
                              void* d_out, int out_size, void* d_ws, size_t ws_size,
                              hipStream_t stream) {
    const float* pos  = (const float*)d_in[0];
    const float* vel  = (const float*)d_in[1];
    const float* mass = (const float*)d_in[2];
    float* out = (float*)d_out;
    int n = in_sizes[2];
    int blocks = (n + 255) / 256;

    // Two-pass ws: [cursor 2KB][ovf_cnt][tile_off 1.05MB][ovf_rec 1MB][ovf_reg 256KB][regbuf 20MB]
    size_t w_off_ovfcnt  = (size_t)NREG * 4;                        // 2048
    size_t w_off_tileoff = 4096;
    size_t w_off_ovfrec  = w_off_tileoff + (size_t)NREG * (NT2 + 1) * 4;
    size_t w_off_ovfreg  = w_off_ovfrec + (size_t)OVF_MAX * 16;
    size_t w_off_regbuf  = w_off_ovfreg + (size_t)OVF_MAX * 4;
    size_t need_twopass  = w_off_regbuf + (size_t)NREG * RCAP * 16;

    // Sorted-path ws: [counts/cursors 8MB][offsets 8MB][records n*32][partials]
    size_t s_off_offsets  = (size_t)NUM_CELLS * 4;
    size_t s_off_records  = s_off_offsets + (size_t)NUM_CELLS * 4;
    size_t s_off_partials = s_off_records + (size_t)n * 32;
    size_t need_sorted    = s_off_partials + (size_t)SCAN_BLKS * 4;

    if (ws_size >= need_twopass) {
        char* ws = (char*)d_ws;
        unsigned int* region_cursor = (unsigned int*)ws;
        int* ovf_cnt           = (int*)(ws + w_off_ovfcnt);
        unsigned int* tile_off = (unsigned int*)(ws + w_off_tileoff);
        uint4* ovf_rec         = (uint4*)(ws + w_off_ovfrec);
        unsigned int* ovf_reg  = (unsigned int*)(ws + w_off_ovfreg);
        uint4* regbuf          = (uint4*)(ws + w_off_regbuf);

        // single memset covers cursor (2048B) + ovf_cnt (4B)
        (void)hipMemsetAsync(ws, 0, 2112, stream);
        region_bin_kernel<<<(n + PPB - 1) / PPB, 1024, 0, stream>>>(
            pos, vel, mass, region_cursor, regbuf, ovf_cnt, ovf_rec, ovf_reg, n);
        tile_sort_kernel<<<NREG, 1024, 0, stream>>>(regbuf, region_cursor,
                                                    tile_off);
        tile_gather2_kernel<<<4096, 512, 0, stream>>>(regbuf, tile_off,
                                                      (float4*)out);
        fixup_packed_kernel<<<16, 256, 0, stream>>>(ovf_cnt, ovf_rec,
                                                    ovf_reg, out);
    } else if (ws_size >= need_sorted) {
        char* ws = (char*)d_ws;
        int* counts   = (int*)ws;                    // reused as cursors
        int* offsets  = (int*)(ws + s_off_offsets);
        float4* records = (float4*)(ws + s_off_records);
        int* partials = (int*)(ws + s_off_partials);

        (void)hipMemsetAsync(counts, 0, (size_t)NUM_CELLS * 4, stream);
        s_hist_kernel<<<blocks, 256, 0, stream>>>(pos, counts, n);
        s_scan_partials_kernel<<<SCAN_BLKS, 256, 0, stream>>>(counts, partials);
        s_scan_tops_kernel<<<1, 1024, 0, stream>>>(partials);
        s_scan_final_kernel<<<SCAN_BLKS, 256, 0, stream>>>(counts, partials,
                                                           offsets, counts);
        s_binplace_kernel<<<blocks, 256, 0, stream>>>(pos, vel, mass, counts,
                                                      records, n);
        s_node_gather_kernel<<<NUM_CELLS / 256, 256, 0, stream>>>(
            records, offsets, counts, (float4*)out);
    } else {
        (void)hipMemsetAsync(out, 0, (size_t)out_size * sizeof(float), stream);
        p2g_scatter_kernel<<<blocks, 256, 0, stream>>>(pos, vel, mass, out, n);
    }
}